// Round 1
// baseline (353.311 us; speedup 1.0000x reference)
//
#include <hip/hip_runtime.h>
#include <math.h>

#define BB 8
#define MM 2048
#define NNP 2048
#define THR2 0.25f
#define NITER 10
#define NPART 17

// ---------------- pack: dest -> float4(x,y,z, valid? |d|^2 : INF), any_valid, init R/t ----------------
__global__ void pack_kernel(const float* __restrict__ pc_dest,
                            const float* __restrict__ init_R,
                            const float* __restrict__ init_t,
                            float4* __restrict__ destp,
                            float* __restrict__ anyvalid,
                            float* __restrict__ Rw,
                            float* __restrict__ tw)
{
    const int b = blockIdx.x;
    const int tid = threadIdx.x;
    __shared__ int anyf;
    if (tid == 0) anyf = 0;
    __syncthreads();
    int local = 0;
    for (int n = tid; n < NNP; n += blockDim.x) {
        float dx = pc_dest[(b * 3 + 0) * NNP + n];
        float dy = pc_dest[(b * 3 + 1) * NNP + n];
        float dz = pc_dest[(b * 3 + 2) * NNP + n];
        int valid = (dx != 0.0f) && (dy != 0.0f) && (dz != 0.0f);
        float dd = dx * dx + dy * dy + dz * dz;
        destp[b * NNP + n] = make_float4(dx, dy, dz, valid ? dd : INFINITY);
        local |= valid;
    }
    if (local) atomicOr(&anyf, 1);
    __syncthreads();
    if (tid == 0) anyvalid[b] = (anyf != 0) ? 1.0f : 0.0f;
    if (tid < 9) Rw[b * 9 + tid] = init_R[b * 9 + tid];
    if (tid < 3) tw[b * 3 + tid] = init_t[b * 3 + tid];
}

// ---------------- corr: one wave per m; lanes split n; write 17 partial sums per m ----------------
__global__ __launch_bounds__(256) void corr_kernel(
    const float* __restrict__ pc_src,
    const float4* __restrict__ destp,
    const float* __restrict__ anyvalid,
    const float* __restrict__ Rw,
    const float* __restrict__ tw,
    float* __restrict__ partials)
{
    const int b = blockIdx.y;
    const int wid = threadIdx.x >> 6;
    const int lane = threadIdx.x & 63;
    const int m = blockIdx.x * 4 + wid;

    const float* Rb = Rw + b * 9;
    const float* tb = tw + b * 3;
    const float R00 = Rb[0], R01 = Rb[1], R02 = Rb[2];
    const float R10 = Rb[3], R11 = Rb[4], R12 = Rb[5];
    const float R20 = Rb[6], R21 = Rb[7], R22 = Rb[8];
    const float t0 = tb[0], t1 = tb[1], t2 = tb[2];

    const float sx = pc_src[0 * MM + m];
    const float sy = pc_src[1 * MM + m];
    const float sz = pc_src[2 * MM + m];

    const float px = R00 * sx + R01 * sy + R02 * sz + t0;
    const float py = R10 * sx + R11 * sy + R12 * sz + t1;
    const float pz = R20 * sx + R21 * sy + R22 * sz + t2;
    const float pp = px * px + py * py + pz * pz;

    const float4* db = destp + b * NNP;
    float best = INFINITY;
    int bestn = 0;
    #pragma unroll 4
    for (int i = 0; i < NNP / 64; ++i) {
        const int n = i * 64 + lane;
        const float4 d = db[n];
        const float dot = px * d.x + py * d.y + pz * d.z;
        const float d2 = (pp + d.w) - 2.0f * dot;
        if (d2 < best) { best = d2; bestn = n; }
    }
    // cross-lane argmin with first-index tie-break (matches jnp.argmin)
    #pragma unroll
    for (int off = 32; off >= 1; off >>= 1) {
        const float ov = __shfl_xor(best, off);
        const int on = __shfl_xor(bestn, off);
        if (ov < best || (ov == best && on < bestn)) { best = ov; bestn = on; }
    }

    const float4 q = db[bestn];
    const float ex = px - q.x, ey = py - q.y, ez = pz - q.z;
    const float d2m = ex * ex + ey * ey + ez * ez;
    const float w = (d2m < THR2) ? anyvalid[b] : 0.0f;

    if (lane == 0) {
        float* pr = partials + (size_t)(b * MM + m) * NPART;
        pr[0] = w;
        pr[1] = w * sx; pr[2] = w * sy; pr[3] = w * sz;
        pr[4] = w * q.x; pr[5] = w * q.y; pr[6] = w * q.z;
        pr[7]  = w * sx * q.x; pr[8]  = w * sx * q.y; pr[9]  = w * sx * q.z;
        pr[10] = w * sy * q.x; pr[11] = w * sy * q.y; pr[12] = w * sy * q.z;
        pr[13] = w * sz * q.x; pr[14] = w * sz * q.y; pr[15] = w * sz * q.z;
        pr[16] = w * d2m;
    }
}

// ---------------- Kabsch via Jacobi eigen of H^T H (double) ----------------
__device__ void kabsch3(const double H[3][3], double R[3][3])
{
    double A[3][3];
    for (int i = 0; i < 3; ++i)
        for (int j = 0; j < 3; ++j) {
            double s = 0.0;
            for (int k = 0; k < 3; ++k) s += H[k][i] * H[k][j];
            A[i][j] = s;
        }
    double V[3][3] = {{1,0,0},{0,1,0},{0,0,1}};
    const double nrm = A[0][0]*A[0][0] + A[1][1]*A[1][1] + A[2][2]*A[2][2] + 1e-300;
    for (int sweep = 0; sweep < 25; ++sweep) {
        const double off = A[0][1]*A[0][1] + A[0][2]*A[0][2] + A[1][2]*A[1][2];
        if (off < 1e-24 * nrm) break;
        for (int pi = 0; pi < 3; ++pi) {
            const int p = (pi == 2) ? 1 : 0;
            const int q = (pi == 0) ? 1 : 2;
            const double apq = A[p][q];
            if (fabs(apq) == 0.0) continue;
            const double theta = (A[q][q] - A[p][p]) / (2.0 * apq);
            const double t = ((theta >= 0.0) ? 1.0 : -1.0) / (fabs(theta) + sqrt(theta * theta + 1.0));
            const double c = 1.0 / sqrt(t * t + 1.0);
            const double s = t * c;
            const double app = A[p][p], aqq = A[q][q];
            A[p][p] = app - t * apq;
            A[q][q] = aqq + t * apq;
            A[p][q] = 0.0; A[q][p] = 0.0;
            const int r = 3 - p - q;
            const double arp = A[r][p], arq = A[r][q];
            A[r][p] = c * arp - s * arq; A[p][r] = A[r][p];
            A[r][q] = s * arp + c * arq; A[q][r] = A[r][q];
            for (int rr = 0; rr < 3; ++rr) {
                const double vrp = V[rr][p], vrq = V[rr][q];
                V[rr][p] = c * vrp - s * vrq;
                V[rr][q] = s * vrp + c * vrq;
            }
        }
    }
    double lam[3] = {A[0][0], A[1][1], A[2][2]};
    int ord[3] = {0, 1, 2};
    for (int i = 0; i < 2; ++i)
        for (int j = i + 1; j < 3; ++j)
            if (lam[ord[j]] > lam[ord[i]]) { const int tmp = ord[i]; ord[i] = ord[j]; ord[j] = tmp; }
    double Vs[3][3], U[3][3];
    for (int k = 0; k < 3; ++k) {
        const int c0 = ord[k];
        const double sk = sqrt(fmax(lam[c0], 0.0));
        const double inv = (sk > 1e-150) ? 1.0 / sk : 0.0;
        for (int i = 0; i < 3; ++i) {
            Vs[i][k] = V[i][c0];
            U[i][k] = (H[i][0] * V[0][c0] + H[i][1] * V[1][c0] + H[i][2] * V[2][c0]) * inv;
        }
    }
    const double detH = H[0][0] * (H[1][1] * H[2][2] - H[1][2] * H[2][1])
                      - H[0][1] * (H[1][0] * H[2][2] - H[1][2] * H[2][0])
                      + H[0][2] * (H[1][0] * H[2][1] - H[1][1] * H[2][0]);
    const double d = (detH < 0.0) ? -1.0 : 1.0;
    for (int i = 0; i < 3; ++i)
        for (int j = 0; j < 3; ++j)
            R[i][j] = Vs[i][0] * U[j][0] + Vs[i][1] * U[j][1] + d * Vs[i][2] * U[j][2];
}

// ---------------- update: reduce partials, solve Kabsch, write new R/t ----------------
__global__ __launch_bounds__(256) void update_kernel(const float* __restrict__ partials,
                                                     float* __restrict__ Rw,
                                                     float* __restrict__ tw)
{
    const int b = blockIdx.x;
    const int tid = threadIdx.x;
    const int lane = tid & 63;
    const int wid = tid >> 6;

    float acc[NPART];
    #pragma unroll
    for (int k = 0; k < NPART; ++k) acc[k] = 0.0f;
    for (int r = tid; r < MM; r += 256) {
        const float* pr = partials + (size_t)(b * MM + r) * NPART;
        #pragma unroll
        for (int k = 0; k < NPART; ++k) acc[k] += pr[k];
    }
    #pragma unroll
    for (int k = 0; k < NPART; ++k) {
        float v = acc[k];
        v += __shfl_xor(v, 32);
        v += __shfl_xor(v, 16);
        v += __shfl_xor(v, 8);
        v += __shfl_xor(v, 4);
        v += __shfl_xor(v, 2);
        v += __shfl_xor(v, 1);
        acc[k] = v;
    }
    __shared__ float sm[4][NPART];
    if (lane == 0) {
        #pragma unroll
        for (int k = 0; k < NPART; ++k) sm[wid][k] = acc[k];
    }
    __syncthreads();
    if (tid != 0) return;

    double S[NPART];
    #pragma unroll
    for (int k = 0; k < NPART; ++k)
        S[k] = (double)sm[0][k] + (double)sm[1][k] + (double)sm[2][k] + (double)sm[3][k];

    const double wsum = S[0];
    if (wsum < 0.5) return;  // keep previous R, t (matches `ok` mask)
    const double safe = (wsum < 1.0) ? 1.0 : wsum;

    double mup[3], muq[3];
    for (int i = 0; i < 3; ++i) { mup[i] = S[1 + i] / safe; muq[i] = S[4 + i] / safe; }

    double H[3][3];
    for (int i = 0; i < 3; ++i)
        for (int j = 0; j < 3; ++j)
            H[i][j] = S[7 + i * 3 + j] - S[1 + i] * S[4 + j] / safe;

    double R[3][3];
    kabsch3(H, R);

    for (int i = 0; i < 3; ++i) {
        for (int j = 0; j < 3; ++j) Rw[b * 9 + i * 3 + j] = (float)R[i][j];
        tw[b * 3 + i] = (float)(muq[i] - (R[i][0] * mup[0] + R[i][1] * mup[1] + R[i][2] * mup[2]));
    }
}

// ---------------- finalize: rmse + copy outputs ----------------
__global__ __launch_bounds__(256) void finalize_kernel(const float* __restrict__ partials,
                                                       const float* __restrict__ Rw,
                                                       const float* __restrict__ tw,
                                                       float* __restrict__ out)
{
    const int b = blockIdx.x;
    const int tid = threadIdx.x;
    const int lane = tid & 63;
    const int wid = tid >> 6;

    float a0 = 0.0f, a1 = 0.0f;
    for (int r = tid; r < MM; r += 256) {
        const float* pr = partials + (size_t)(b * MM + r) * NPART;
        a0 += pr[0];
        a1 += pr[16];
    }
    #pragma unroll
    for (int off = 32; off >= 1; off >>= 1) {
        a0 += __shfl_xor(a0, off);
        a1 += __shfl_xor(a1, off);
    }
    __shared__ float s0[4], s1[4];
    if (lane == 0) { s0[wid] = a0; s1[wid] = a1; }
    __syncthreads();
    if (tid == 0) {
        const float wsum = s0[0] + s0[1] + s0[2] + s0[3];
        const float wd2 = s1[0] + s1[1] + s1[2] + s1[3];
        const float safe = fmaxf(wsum, 1.0f);
        const float rmse = sqrtf(wd2 / safe);
        out[96 + b] = (wsum > 0.0f) ? rmse : __builtin_nanf("");
    }
    if (tid < 9) out[b * 9 + tid] = Rw[b * 9 + tid];
    if (tid < 3) out[72 + b * 3 + tid] = tw[b * 3 + tid];
}

extern "C" void kernel_launch(void* const* d_in, const int* in_sizes, int n_in,
                              void* d_out, int out_size, void* d_ws, size_t ws_size,
                              hipStream_t stream) {
    const float* pc_src  = (const float*)d_in[0];
    const float* pc_dest = (const float*)d_in[1];
    const float* init_R  = (const float*)d_in[2];
    const float* init_t  = (const float*)d_in[3];
    float* out = (float*)d_out;
    float* ws = (float*)d_ws;

    // ws layout (floats)
    float4* destp   = (float4*)ws;                 // BB*NNP*4
    float* anyvalid = ws + BB * NNP * 4;           // BB
    float* Rw       = anyvalid + BB;               // BB*9
    float* tw       = Rw + BB * 9;                 // BB*3
    float* partials = tw + BB * 3;                 // BB*MM*NPART

    pack_kernel<<<BB, 256, 0, stream>>>(pc_dest, init_R, init_t, destp, anyvalid, Rw, tw);

    for (int it = 0; it < NITER; ++it) {
        corr_kernel<<<dim3(MM / 4, BB), 256, 0, stream>>>(pc_src, destp, anyvalid, Rw, tw, partials);
        update_kernel<<<BB, 256, 0, stream>>>(partials, Rw, tw);
    }
    corr_kernel<<<dim3(MM / 4, BB), 256, 0, stream>>>(pc_src, destp, anyvalid, Rw, tw, partials);
    finalize_kernel<<<BB, 256, 0, stream>>>(partials, Rw, tw, out);
}